// Round 1
// baseline (16039.766 us; speedup 1.0000x reference)
//
#include <hip/hip_runtime.h>
#include <math.h>

// Problem constants
#define T_SEQ 256
#define BATCH 128
#define HIDDEN 512
#define NLAYERS 4
// d_out layout: out [128][256][768] | hT [4][128][512] | cT [4][128][512]
#define OUT_ELEMS   25165824u        // 128*256*768
#define HT_OFF      25165824u
#define CT_OFF      25427968u        // HT_OFF + 4*128*512
// ws layout: h_all [4][257][128][512] fp32, then counters [4*256] u32
#define HALL_FLOATS 67371008u        // 4*257*128*512
// pipeline LDS (floats): W 32*1024 | gates 128*33 | c 128*8 | bias 32
#define PIPE_LDS_FLOATS (32*1024 + 128*33 + 128*8 + 32)
#define PIPE_LDS_BYTES  (PIPE_LDS_FLOATS*4)

// ---------------------------------------------------------------------------
// init: h_all slot 0 of each layer <- h0 ; zero flags
// ---------------------------------------------------------------------------
__global__ void init_kernel(float* __restrict__ h_all, unsigned* __restrict__ cnt,
                            const float* __restrict__ h0) {
    int idx = blockIdx.x * 256 + threadIdx.x;
    if (idx < NLAYERS * BATCH * HIDDEN) {           // 262144
        int l = idx >> 16;                           // /65536
        int rest = idx & 65535;
        h_all[((size_t)(l * 257) << 16) + rest] = h0[idx];
    }
    if (idx < NLAYERS * T_SEQ) cnt[idx] = 0u;
}

// ---------------------------------------------------------------------------
// Generic 128x128-tile fp32 GEMM body: C[m][n] = sum_k A[m][k]*B[n][k] + bias[n]
// A: 128 rows, row stride lda. B row-major [n][K]. 256 threads, 8x8 micro-tile.
// ---------------------------------------------------------------------------
__device__ __forceinline__ void gemm_tile(const float* __restrict__ A, int lda,
                                          const float* __restrict__ B, int K,
                                          const float* __restrict__ bias,
                                          float* __restrict__ C, int ldc,
                                          int ntile) {
    __shared__ float As[16][132];
    __shared__ float Bs[16][132];
    const int tid = threadIdx.x;
    const int tx = tid & 15, ty = tid >> 4;
    const float* Bb = B + (size_t)ntile * 128 * K;
    const float* biasp = bias + ntile * 128;
    float* Cp = C + ntile * 128;

    float acc[8][8];
#pragma unroll
    for (int i = 0; i < 8; ++i)
#pragma unroll
        for (int j = 0; j < 8; ++j) acc[i][j] = 0.f;

    for (int k0 = 0; k0 < K; k0 += 16) {
        __syncthreads();
#pragma unroll
        for (int qq = 0; qq < 2; ++qq) {
            int q = tid + qq * 256;
            int r = q >> 2, kq = q & 3;
            float4 va = *(const float4*)(A + (size_t)r * lda + k0 + (kq << 2));
            As[(kq << 2) + 0][r] = va.x; As[(kq << 2) + 1][r] = va.y;
            As[(kq << 2) + 2][r] = va.z; As[(kq << 2) + 3][r] = va.w;
            float4 vb = *(const float4*)(Bb + (size_t)r * K + k0 + (kq << 2));
            Bs[(kq << 2) + 0][r] = vb.x; Bs[(kq << 2) + 1][r] = vb.y;
            Bs[(kq << 2) + 2][r] = vb.z; Bs[(kq << 2) + 3][r] = vb.w;
        }
        __syncthreads();
#pragma unroll
        for (int k = 0; k < 16; ++k) {
            float a0[8], b0[8];
            *(float4*)&a0[0] = *(const float4*)&As[k][tx << 2];
            *(float4*)&a0[4] = *(const float4*)&As[k][(tx << 2) + 64];
            *(float4*)&b0[0] = *(const float4*)&Bs[k][ty << 2];
            *(float4*)&b0[4] = *(const float4*)&Bs[k][(ty << 2) + 64];
#pragma unroll
            for (int i = 0; i < 8; ++i)
#pragma unroll
                for (int j = 0; j < 8; ++j)
                    acc[i][j] = fmaf(a0[i], b0[j], acc[i][j]);
        }
    }
#pragma unroll
    for (int i = 0; i < 8; ++i) {
        int m = (i < 4) ? ((tx << 2) + i) : ((tx << 2) + 64 + (i - 4));
        float* Crow = Cp + (size_t)m * ldc;
#pragma unroll
        for (int j = 0; j < 8; ++j) {
            int n = (j < 4) ? ((ty << 2) + j) : ((ty << 2) + 64 + (j - 4));
            Crow[n] = acc[i][j] + biasp[n];
        }
    }
}

// xp[t][b][j] = sum_k x[b][t][k] * W_in[j][k] + b_in[j]
__global__ __launch_bounds__(256) void gemm_xp_kernel(const float* __restrict__ x,
                                                      const float* __restrict__ W_in,
                                                      const float* __restrict__ b_in,
                                                      float* __restrict__ xp) {
    int t = blockIdx.x;
    gemm_tile(x + (size_t)t * 768, 196608, W_in, 768, b_in,
              xp + ((size_t)t << 16), 512, blockIdx.y);
}

// out[b][t][o] = sum_j h3[t][b][j] * W_out[o][j] + b_out[o]
__global__ __launch_bounds__(256) void gemm_out_kernel(const float* __restrict__ h_all,
                                                       const float* __restrict__ W_out,
                                                       const float* __restrict__ b_out,
                                                       float* __restrict__ out) {
    int bx = blockIdx.x;
    int b = bx >> 1, th = bx & 1;
    int t0 = th << 7;
    const float* A = h_all + ((size_t)(3 * 257 + t0 + 1) << 16) + ((size_t)b << 9);
    float* Cb = out + (size_t)b * 196608 + (size_t)t0 * 768;
    gemm_tile(A, 65536, W_out, 512, b_out, Cb, 768, blockIdx.y);
}

// ---------------------------------------------------------------------------
// Persistent pipelined LSTM. 256 blocks = 4 layers x 64 col-chunks, 512 thr.
// Block (l,c) owns hidden cols [8c,8c+8) of layer l for ALL 128 batch rows.
// Weights [W_ih|W_hh] slice (32 gate rows x 1024) live in LDS, XOR-swizzled.
// Cross-block dependencies via agent-scope release/acquire counters.
// ---------------------------------------------------------------------------
__global__ __launch_bounds__(512) void lstm_pipeline(
    const float* __restrict__ xp,       // [256][128][512] (head of d_out)
    float* __restrict__ h_all,          // [4][257][128][512]
    unsigned* __restrict__ cnt,         // [4][256]
    const float* __restrict__ W_ih, const float* __restrict__ W_hh,
    const float* __restrict__ b_ih, const float* __restrict__ b_hh,
    const float* __restrict__ c0,
    float* __restrict__ d_out) {
    extern __shared__ float lds[];
    float4* Wq = (float4*)lds;                   // 32*256 quads
    float* gatesL = lds + 32 * 1024;             // [128][33]
    float* cL = gatesL + 128 * 33;               // [128][8]
    float* biasL = cL + 128 * 8;                 // [32]

    const int tid = threadIdx.x;
    const int l = blockIdx.x >> 6;
    const int c = blockIdx.x & 63;

    // --- stage weight slice into LDS (once) ---
    for (int i = 0; i < 16; ++i) {
        int q = tid + (i << 9);
        int u = q >> 8, kqt = q & 255;
        int gr = ((u >> 3) << 9) + (c << 3) + (u & 7);   // global gate row
        int k = kqt << 2;
        const float* src = (k < 512)
            ? (W_ih + (((size_t)l * 2048 + gr) << 9) + k)
            : (W_hh + (((size_t)l * 2048 + gr) << 9) + (k - 512));
        Wq[(u << 8) + (kqt ^ ((u >> 3) << 1))] = *(const float4*)src;
    }
    if (tid < 32) {
        int u = tid;
        int gr = ((u >> 3) << 9) + (c << 3) + (u & 7);
        biasL[u] = b_ih[l * 2048 + gr] + b_hh[l * 2048 + gr];
    }
    for (int p = tid; p < 1024; p += 512) {
        int r = p >> 3, hc = p & 7;
        cL[p] = c0[((size_t)l << 16) + (r << 9) + (c << 3) + hc];
    }
    __syncthreads();

    const int row = tid >> 2;        // 0..127 batch row
    const int gcg = tid & 3;         // gate-col group (8 gate rows each)
    const int ubase = gcg << 3;
    const int swz = gcg << 1;        // LDS xor swizzle (bank spread)

    for (int t = 0; t < T_SEQ; ++t) {
        if (tid == 0) {
            if (l > 0) {
                while (__hip_atomic_load(&cnt[((l - 1) << 8) + t], __ATOMIC_ACQUIRE,
                                         __HIP_MEMORY_SCOPE_AGENT) < 64u)
                    __builtin_amdgcn_s_sleep(1);
            }
            if (t > 0) {
                while (__hip_atomic_load(&cnt[(l << 8) + t - 1], __ATOMIC_ACQUIRE,
                                         __HIP_MEMORY_SCOPE_AGENT) < 64u)
                    __builtin_amdgcn_s_sleep(1);
            }
        }
        __syncthreads();

        const float4* xin4 = (const float4*)((l == 0)
            ? (xp + ((size_t)t << 16))
            : (h_all + ((size_t)((l - 1) * 257 + t + 1) << 16)));
        const float4* hs4 = (const float4*)(h_all + ((size_t)(l * 257 + t) << 16));
        const float4* xrow = xin4 + (row << 7);
        const float4* hrow = hs4 + (row << 7);

        float acc[8];
#pragma unroll
        for (int j = 0; j < 8; ++j) acc[j] = biasL[ubase + j];

#pragma unroll 2
        for (int kq = 0; kq < 128; ++kq) {
            float4 xv = xrow[kq];
#pragma unroll
            for (int j = 0; j < 8; ++j) {
                float4 wv = Wq[((ubase + j) << 8) + (kq ^ swz)];
                acc[j] = fmaf(xv.x, wv.x, acc[j]);
                acc[j] = fmaf(xv.y, wv.y, acc[j]);
                acc[j] = fmaf(xv.z, wv.z, acc[j]);
                acc[j] = fmaf(xv.w, wv.w, acc[j]);
            }
        }
#pragma unroll 2
        for (int kq = 0; kq < 128; ++kq) {
            float4 xv = hrow[kq];
#pragma unroll
            for (int j = 0; j < 8; ++j) {
                float4 wv = Wq[((ubase + j) << 8) + ((128 + kq) ^ swz)];
                acc[j] = fmaf(xv.x, wv.x, acc[j]);
                acc[j] = fmaf(xv.y, wv.y, acc[j]);
                acc[j] = fmaf(xv.z, wv.z, acc[j]);
                acc[j] = fmaf(xv.w, wv.w, acc[j]);
            }
        }
#pragma unroll
        for (int j = 0; j < 8; ++j) gatesL[row * 33 + ubase + j] = acc[j];
        __syncthreads();

        // c/h update: 1024 (row,hc) pairs, 2 per thread
#pragma unroll
        for (int it = 0; it < 2; ++it) {
            int p = tid + (it << 9);
            int r = p >> 3, hc = p & 7;
            float iv = gatesL[r * 33 + hc];
            float fv = gatesL[r * 33 + 8 + hc];
            float gv = gatesL[r * 33 + 16 + hc];
            float ov = gatesL[r * 33 + 24 + hc];
            float ig = 1.f / (1.f + __expf(-iv));
            float fg = 1.f / (1.f + __expf(-fv));
            float gg = tanhf(gv);
            float og = 1.f / (1.f + __expf(-ov));
            float cn = fg * cL[p] + ig * gg;
            float hn = og * tanhf(cn);
            cL[p] = cn;
            size_t off = ((size_t)(l * 257 + t + 1) << 16) + (r << 9) + (c << 3) + hc;
            h_all[off] = hn;
            if (t == T_SEQ - 1) {
                size_t fo = ((size_t)l << 16) + (r << 9) + (c << 3) + hc;
                d_out[HT_OFF + fo] = hn;
                d_out[CT_OFF + fo] = cn;
            }
        }
        __syncthreads();
        if (tid == 0) {
            __hip_atomic_fetch_add(&cnt[(l << 8) + t], 1u, __ATOMIC_RELEASE,
                                   __HIP_MEMORY_SCOPE_AGENT);
        }
    }
}

// ---------------------------------------------------------------------------
// LayerNorm over last dim (768), in place on d_out
// ---------------------------------------------------------------------------
__global__ __launch_bounds__(256) void ln_kernel(float* __restrict__ out,
                                                 const float* __restrict__ g,
                                                 const float* __restrict__ bvec) {
    float* p = out + (size_t)blockIdx.x * 768;
    int tid = threadIdx.x;
    float v0 = p[tid], v1 = p[tid + 256], v2 = p[tid + 512];
    float s = v0 + v1 + v2;
    float q = v0 * v0 + v1 * v1 + v2 * v2;
    for (int off = 32; off > 0; off >>= 1) {
        s += __shfl_down(s, off);
        q += __shfl_down(q, off);
    }
    __shared__ float ss[4], qq[4];
    __shared__ float mu_s, rs_s;
    int w = tid >> 6;
    if ((tid & 63) == 0) { ss[w] = s; qq[w] = q; }
    __syncthreads();
    if (tid == 0) {
        float S = ss[0] + ss[1] + ss[2] + ss[3];
        float Q = qq[0] + qq[1] + qq[2] + qq[3];
        float mu = S * (1.f / 768.f);
        float var = Q * (1.f / 768.f) - mu * mu;
        mu_s = mu;
        rs_s = rsqrtf(var + 1e-5f);
    }
    __syncthreads();
    float mu = mu_s, rs = rs_s;
    p[tid]       = (v0 - mu) * rs * g[tid]       + bvec[tid];
    p[tid + 256] = (v1 - mu) * rs * g[tid + 256] + bvec[tid + 256];
    p[tid + 512] = (v2 - mu) * rs * g[tid + 512] + bvec[tid + 512];
}

// ---------------------------------------------------------------------------
extern "C" void kernel_launch(void* const* d_in, const int* in_sizes, int n_in,
                              void* d_out, int out_size, void* d_ws, size_t ws_size,
                              hipStream_t stream) {
    (void)in_sizes; (void)n_in; (void)out_size; (void)ws_size;
    const float* x     = (const float*)d_in[0];
    const float* h0    = (const float*)d_in[1];
    const float* c0    = (const float*)d_in[2];
    const float* W_in  = (const float*)d_in[3];
    const float* b_in  = (const float*)d_in[4];
    const float* W_ih  = (const float*)d_in[5];
    const float* W_hh  = (const float*)d_in[6];
    const float* b_ih  = (const float*)d_in[7];
    const float* b_hh  = (const float*)d_in[8];
    const float* W_out = (const float*)d_in[9];
    const float* b_out = (const float*)d_in[10];
    const float* ln_g  = (const float*)d_in[11];
    const float* ln_b  = (const float*)d_in[12];

    float* out = (float*)d_out;
    float* h_all = (float*)d_ws;                                  // 257-slot time buffer
    unsigned* cnt = (unsigned*)((char*)d_ws + (size_t)HALL_FLOATS * 4);
    float* xp = out;   // borrow head of d_out for xp[256][128][512]; overwritten later

    (void)hipFuncSetAttribute(reinterpret_cast<const void*>(lstm_pipeline),
                              hipFuncAttributeMaxDynamicSharedMemorySize,
                              PIPE_LDS_BYTES);

    init_kernel<<<1024, 256, 0, stream>>>(h_all, cnt, h0);
    gemm_xp_kernel<<<dim3(256, 4), 256, 0, stream>>>(x, W_in, b_in, xp);
    lstm_pipeline<<<256, 512, PIPE_LDS_BYTES, stream>>>(xp, h_all, cnt, W_ih, W_hh,
                                                        b_ih, b_hh, c0, out);
    gemm_out_kernel<<<dim3(256, 6), 256, 0, stream>>>(h_all, W_out, b_out, out);
    ln_kernel<<<32768, 256, 0, stream>>>(out, ln_g, ln_b);
}

// Round 2
// 9754.250 us; speedup vs baseline: 1.6444x; 1.6444x over previous
//
#include <hip/hip_runtime.h>
#include <math.h>

#define T_SEQ 256
#define BATCH 128
#define HID 512
#define NL 4
// d_out: out [128][256][768] fp32 | hT [4][128][512] | cT [4][128][512]
#define HT_OFF 25165824u
#define CT_OFF 25427968u
// ws: h_all bf16 [4][257][128][512] | xp bf16 [256][128][512] | flags
#define HALL_ELEMS 67371008u
#define XP_ELEMS   16777216u
#define WB_STRIDE  1032                         // bf16 row stride (pad 8)
#define PIPE_LDS   (32*1032*2 + 128*33*4 + 128*8*4 + 32*4)
#define FLAGS(l,t) ((((l) << 8) + (t)) << 4)    // 64-B spaced flags

typedef __attribute__((ext_vector_type(8))) short bf16x8;
typedef __attribute__((ext_vector_type(4))) float f32x4;

__device__ __forceinline__ short f2bf(float f) {
    unsigned u = __float_as_uint(f);
    u = (u + 0x7fffu + ((u >> 16) & 1u)) >> 16;
    return (short)u;
}
__device__ __forceinline__ unsigned pack2(float a, float b) {
    return ((unsigned)(unsigned short)f2bf(a)) |
           (((unsigned)(unsigned short)f2bf(b)) << 16);
}

// ---------------------------------------------------------------------------
__global__ void init_kernel(short* __restrict__ h_all, unsigned* __restrict__ cnt,
                            const float* __restrict__ h0) {
    int idx = blockIdx.x * 256 + threadIdx.x;       // grid 1024*256
    if (idx < NL * BATCH * HID) {
        int l = idx >> 16, rest = idx & 65535;
        h_all[((size_t)(l * 257) << 16) + rest] = f2bf(h0[idx]);
    }
    if (idx < NL * T_SEQ * 16) cnt[idx] = 0u;
}

// ---------------------------------------------------------------------------
// xp-GEMM: xp[t][b][n] (bf16) = x[b][t][:768] @ W_in[n][:768] + b_in[n]
// block tile 128x128, 256 thr = 4 waves, each 2 rt x 8 ct.
// ---------------------------------------------------------------------------
__global__ __launch_bounds__(256) void gemm_xp(const float* __restrict__ x,
                                               const float* __restrict__ W_in,
                                               const float* __restrict__ b_in,
                                               short* __restrict__ xp) {
    __shared__ short As[128 * 72];
    __shared__ short Bs[128 * 72];
    const int tid = threadIdx.x;
    const int w = tid >> 6, lane = tid & 63;
    const int m = lane & 15, quad = lane >> 4;
    const int rowbase = blockIdx.x * 128;           // M = 32768 (b*256+t)
    const int colbase = blockIdx.y * 128;           // N = 512
    f32x4 acc[2][8];
#pragma unroll
    for (int rt = 0; rt < 2; ++rt)
#pragma unroll
        for (int ct = 0; ct < 8; ++ct) { f32x4 z = {0.f,0.f,0.f,0.f}; acc[rt][ct] = z; }

    for (int k0 = 0; k0 < 768; k0 += 64) {
        __syncthreads();
#pragma unroll
        for (int i = 0; i < 8; ++i) {               // A: 128 rows x 64 k fp32->bf16
            int q = tid + (i << 8);
            int r = q >> 4, f4 = (q & 15) << 2;
            float4 v = *(const float4*)(x + (size_t)(rowbase + r) * 768 + k0 + f4);
            uint2 p; p.x = pack2(v.x, v.y); p.y = pack2(v.z, v.w);
            *(uint2*)&As[r * 72 + f4] = p;
        }
#pragma unroll
        for (int i = 0; i < 8; ++i) {               // B: W_in rows
            int q = tid + (i << 8);
            int r = q >> 4, f4 = (q & 15) << 2;
            float4 v = *(const float4*)(W_in + (size_t)(colbase + r) * 768 + k0 + f4);
            uint2 p; p.x = pack2(v.x, v.y); p.y = pack2(v.z, v.w);
            *(uint2*)&Bs[r * 72 + f4] = p;
        }
        __syncthreads();
#pragma unroll
        for (int ks = 0; ks < 2; ++ks) {
            int kof = (ks << 5) + (quad << 3);
            bf16x8 a0 = *(const bf16x8*)&As[((w * 2 + 0) * 16 + m) * 72 + kof];
            bf16x8 a1 = *(const bf16x8*)&As[((w * 2 + 1) * 16 + m) * 72 + kof];
#pragma unroll
            for (int ct = 0; ct < 8; ++ct) {
                bf16x8 b = *(const bf16x8*)&Bs[(ct * 16 + m) * 72 + kof];
                acc[0][ct] = __builtin_amdgcn_mfma_f32_16x16x32_bf16(a0, b, acc[0][ct], 0, 0, 0);
                acc[1][ct] = __builtin_amdgcn_mfma_f32_16x16x32_bf16(a1, b, acc[1][ct], 0, 0, 0);
            }
        }
    }
    float bias_r[8];
#pragma unroll
    for (int ct = 0; ct < 8; ++ct) bias_r[ct] = b_in[colbase + ct * 16 + m];
#pragma unroll
    for (int rt = 0; rt < 2; ++rt)
#pragma unroll
        for (int reg = 0; reg < 4; ++reg) {
            int m_glob = rowbase + (w * 2 + rt) * 16 + quad * 4 + reg;
            int t = m_glob & 255, b = m_glob >> 8;
            short* dst = xp + (((size_t)(t << 7) + b) << 9);
#pragma unroll
            for (int ct = 0; ct < 8; ++ct)
                dst[colbase + ct * 16 + m] = f2bf(acc[rt][ct][reg] + bias_r[ct]);
        }
}

// ---------------------------------------------------------------------------
// out-GEMM: out[b][t][n] (fp32) = h3[t][b][:512] @ W_out[n][:512] + b_out[n]
// ---------------------------------------------------------------------------
__global__ __launch_bounds__(256) void gemm_out(const short* __restrict__ h3,
                                                const float* __restrict__ W_out,
                                                const float* __restrict__ b_out,
                                                float* __restrict__ out) {
    __shared__ short As[128 * 72];
    __shared__ short Bs[128 * 72];
    const int tid = threadIdx.x;
    const int w = tid >> 6, lane = tid & 63;
    const int m = lane & 15, quad = lane >> 4;
    const int rowbase = blockIdx.x * 128;           // M = 32768 (t*128+b)
    const int colbase = blockIdx.y * 128;           // N = 768
    f32x4 acc[2][8];
#pragma unroll
    for (int rt = 0; rt < 2; ++rt)
#pragma unroll
        for (int ct = 0; ct < 8; ++ct) { f32x4 z = {0.f,0.f,0.f,0.f}; acc[rt][ct] = z; }

    for (int k0 = 0; k0 < 512; k0 += 64) {
        __syncthreads();
#pragma unroll
        for (int i = 0; i < 4; ++i) {               // A bf16 direct: 128 rows x 64 k
            int q = tid + (i << 8);
            int r = q >> 3, seg = (q & 7) << 3;
            *(bf16x8*)&As[r * 72 + seg] =
                *(const bf16x8*)(h3 + (size_t)(rowbase + r) * 512 + k0 + seg);
        }
#pragma unroll
        for (int i = 0; i < 8; ++i) {               // B: W_out fp32->bf16
            int q = tid + (i << 8);
            int r = q >> 4, f4 = (q & 15) << 2;
            float4 v = *(const float4*)(W_out + (size_t)(colbase + r) * 512 + k0 + f4);
            uint2 p; p.x = pack2(v.x, v.y); p.y = pack2(v.z, v.w);
            *(uint2*)&Bs[r * 72 + f4] = p;
        }
        __syncthreads();
#pragma unroll
        for (int ks = 0; ks < 2; ++ks) {
            int kof = (ks << 5) + (quad << 3);
            bf16x8 a0 = *(const bf16x8*)&As[((w * 2 + 0) * 16 + m) * 72 + kof];
            bf16x8 a1 = *(const bf16x8*)&As[((w * 2 + 1) * 16 + m) * 72 + kof];
#pragma unroll
            for (int ct = 0; ct < 8; ++ct) {
                bf16x8 b = *(const bf16x8*)&Bs[(ct * 16 + m) * 72 + kof];
                acc[0][ct] = __builtin_amdgcn_mfma_f32_16x16x32_bf16(a0, b, acc[0][ct], 0, 0, 0);
                acc[1][ct] = __builtin_amdgcn_mfma_f32_16x16x32_bf16(a1, b, acc[1][ct], 0, 0, 0);
            }
        }
    }
    float bias_r[8];
#pragma unroll
    for (int ct = 0; ct < 8; ++ct) bias_r[ct] = b_out[colbase + ct * 16 + m];
#pragma unroll
    for (int rt = 0; rt < 2; ++rt)
#pragma unroll
        for (int reg = 0; reg < 4; ++reg) {
            int m_glob = rowbase + (w * 2 + rt) * 16 + quad * 4 + reg;
            int t = m_glob >> 7, b = m_glob & 127;
            float* dst = out + (size_t)b * 196608 + (size_t)t * 768;
#pragma unroll
            for (int ct = 0; ct < 8; ++ct)
                dst[colbase + ct * 16 + m] = acc[rt][ct][reg] + bias_r[ct];
        }
}

// ---------------------------------------------------------------------------
// Persistent MFMA LSTM pipeline. 256 blocks = 4 layers x 64 col-chunks,
// 512 thr = 8 waves: waves 0-3 x-part (K 0..511), waves 4-7 h-part (K 512..1023).
// Weights bf16 in LDS; gate accum fp32 in LDS; c fp32 in LDS; h bf16 global.
// ---------------------------------------------------------------------------
__global__ __launch_bounds__(512) void lstm_pipeline(
    const short* __restrict__ xp, short* __restrict__ h_all,
    unsigned* __restrict__ cnt,
    const float* __restrict__ W_ih, const float* __restrict__ W_hh,
    const float* __restrict__ b_ih, const float* __restrict__ b_hh,
    const float* __restrict__ c0, float* __restrict__ d_out) {
    extern __shared__ char lds[];
    short* Wb    = (short*)lds;                          // [32][1032] bf16
    float* gates = (float*)(lds + 32 * WB_STRIDE * 2);   // [128][33] fp32
    float* cL    = gates + 128 * 33;                     // [128][8]
    float* biasL = cL + 128 * 8;                         // [32]

    const int tid = threadIdx.x;
    const int l = blockIdx.x >> 6, c = blockIdx.x & 63;

    // --- stage weights (fp32 -> bf16), bias, c0 ---
#pragma unroll
    for (int i = 0; i < 16; ++i) {
        int q = tid + (i << 9);                 // 0..8191 quads
        int u = q >> 8, kq = (q & 255) << 2;    // k element 0..1020
        int gr = ((u >> 3) << 9) + (c << 3) + (u & 7);
        const float* src = (kq < 512)
            ? (W_ih + ((size_t)(l * 2048 + gr) << 9) + kq)
            : (W_hh + ((size_t)(l * 2048 + gr) << 9) + (kq - 512));
        float4 v = *(const float4*)src;
        uint2 p; p.x = pack2(v.x, v.y); p.y = pack2(v.z, v.w);
        *(uint2*)&Wb[u * WB_STRIDE + kq] = p;
    }
    if (tid < 32) {
        int gr = ((tid >> 3) << 9) + (c << 3) + (tid & 7);
        biasL[tid] = b_ih[l * 2048 + gr] + b_hh[l * 2048 + gr];
    }
    for (int p = tid; p < 1024; p += 512) {
        int r = p >> 3, hc = p & 7;
        cL[p] = c0[((size_t)l << 16) + (r << 9) + (c << 3) + hc];
    }
    __syncthreads();

    const int w = tid >> 6, lane = tid & 63;
    const int m = lane & 15, quad = lane >> 4;
    const bool hw = (w >= 4);
    const int w2 = w & 3;
    const int r0 = w2 * 32 + m;                 // A row for rt=0
    const int gb0 = w2 * 32 + quad * 4;         // gate row base for rt=0
    const int kbase = hw ? 512 : 0;             // weight K offset

    for (int t = 0; t < T_SEQ; ++t) {
        // --- wait for this phase's dependency ---
        if (hw) {
            if (t > 0) {
                const unsigned* f = &cnt[FLAGS(l, t - 1)];
                while (__hip_atomic_load(f, __ATOMIC_ACQUIRE, __HIP_MEMORY_SCOPE_AGENT) < 64u)
                    __builtin_amdgcn_s_sleep(2);
            }
        } else if (l > 0) {
            const unsigned* f = &cnt[FLAGS(l - 1, t)];
            while (__hip_atomic_load(f, __ATOMIC_ACQUIRE, __HIP_MEMORY_SCOPE_AGENT) < 64u)
                __builtin_amdgcn_s_sleep(2);
        }

        const short* src = hw
            ? (h_all + ((size_t)(l * 257 + t) << 16))
            : ((l == 0) ? (xp + ((size_t)t << 16))
                        : (h_all + ((size_t)((l - 1) * 257 + t + 1) << 16)));

        f32x4 z = {0.f, 0.f, 0.f, 0.f};
        f32x4 acc00 = z, acc01 = z, acc10 = z, acc11 = z;
#pragma unroll 4
        for (int ks = 0; ks < 16; ++ks) {
            int ka = (ks << 5) + (quad << 3);
            bf16x8 a0 = *(const bf16x8*)(src + ((size_t)r0 << 9) + ka);
            bf16x8 a1 = *(const bf16x8*)(src + ((size_t)(r0 + 16) << 9) + ka);
            int kw = kbase + ka;
            bf16x8 b0 = *(const bf16x8*)&Wb[m * WB_STRIDE + kw];
            bf16x8 b1 = *(const bf16x8*)&Wb[(16 + m) * WB_STRIDE + kw];
            acc00 = __builtin_amdgcn_mfma_f32_16x16x32_bf16(a0, b0, acc00, 0, 0, 0);
            acc01 = __builtin_amdgcn_mfma_f32_16x16x32_bf16(a0, b1, acc01, 0, 0, 0);
            acc10 = __builtin_amdgcn_mfma_f32_16x16x32_bf16(a1, b0, acc10, 0, 0, 0);
            acc11 = __builtin_amdgcn_mfma_f32_16x16x32_bf16(a1, b1, acc11, 0, 0, 0);
        }
        if (!hw) {
#pragma unroll
            for (int reg = 0; reg < 4; ++reg) {
                int b0r = gb0 + reg, b1r = gb0 + 16 + reg;
                gates[b0r * 33 + m]      = acc00[reg];
                gates[b0r * 33 + 16 + m] = acc01[reg];
                gates[b1r * 33 + m]      = acc10[reg];
                gates[b1r * 33 + 16 + m] = acc11[reg];
            }
        }
        __syncthreads();                         // x-part visible
        if (hw) {
#pragma unroll
            for (int reg = 0; reg < 4; ++reg) {
                int b0r = gb0 + reg, b1r = gb0 + 16 + reg;
                gates[b0r * 33 + m]      += acc00[reg];
                gates[b0r * 33 + 16 + m] += acc01[reg];
                gates[b1r * 33 + m]      += acc10[reg];
                gates[b1r * 33 + 16 + m] += acc11[reg];
            }
        }
        __syncthreads();                         // gates complete

        // --- elementwise update: 1024 cells, 2 per thread ---
#pragma unroll
        for (int it = 0; it < 2; ++it) {
            int p = tid + (it << 9);
            int r = p >> 3, hc = p & 7;
            float iv = gates[r * 33 + hc]      + biasL[hc];
            float fv = gates[r * 33 + 8 + hc]  + biasL[8 + hc];
            float gv = gates[r * 33 + 16 + hc] + biasL[16 + hc];
            float ov = gates[r * 33 + 24 + hc] + biasL[24 + hc];
            float ig = 1.f / (1.f + __expf(-iv));
            float fg = 1.f / (1.f + __expf(-fv));
            float gg = tanhf(gv);
            float og = 1.f / (1.f + __expf(-ov));
            float cn = fg * cL[p] + ig * gg;
            float hn = og * tanhf(cn);
            cL[p] = cn;
            h_all[((size_t)(l * 257 + t + 1) << 16) + (r << 9) + (c << 3) + hc] = f2bf(hn);
            if (t == T_SEQ - 1) {
                size_t fo = ((size_t)l << 16) + (size_t)(r << 9) + (c << 3) + hc;
                d_out[HT_OFF + fo] = hn;
                d_out[CT_OFF + fo] = cn;
            }
        }
        __syncthreads();                         // stores drained (vmcnt in barrier)
        if (tid == 0)
            __hip_atomic_fetch_add(&cnt[FLAGS(l, t)], 1u, __ATOMIC_RELEASE,
                                   __HIP_MEMORY_SCOPE_AGENT);
    }
}

// ---------------------------------------------------------------------------
__global__ __launch_bounds__(256) void ln_kernel(float* __restrict__ out,
                                                 const float* __restrict__ g,
                                                 const float* __restrict__ bvec) {
    float* p = out + (size_t)blockIdx.x * 768;
    int tid = threadIdx.x;
    float v0 = p[tid], v1 = p[tid + 256], v2 = p[tid + 512];
    float s = v0 + v1 + v2;
    float q = v0 * v0 + v1 * v1 + v2 * v2;
    for (int off = 32; off > 0; off >>= 1) {
        s += __shfl_down(s, off);
        q += __shfl_down(q, off);
    }
    __shared__ float ss[4], qq[4];
    __shared__ float mu_s, rs_s;
    int w = tid >> 6;
    if ((tid & 63) == 0) { ss[w] = s; qq[w] = q; }
    __syncthreads();
    if (tid == 0) {
        float S = ss[0] + ss[1] + ss[2] + ss[3];
        float Q = qq[0] + qq[1] + qq[2] + qq[3];
        float mu = S * (1.f / 768.f);
        float var = Q * (1.f / 768.f) - mu * mu;
        mu_s = mu;
        rs_s = rsqrtf(var + 1e-5f);
    }
    __syncthreads();
    float mu = mu_s, rs = rs_s;
    p[tid]       = (v0 - mu) * rs * g[tid]       + bvec[tid];
    p[tid + 256] = (v1 - mu) * rs * g[tid + 256] + bvec[tid + 256];
    p[tid + 512] = (v2 - mu) * rs * g[tid + 512] + bvec[tid + 512];
}

// ---------------------------------------------------------------------------
extern "C" void kernel_launch(void* const* d_in, const int* in_sizes, int n_in,
                              void* d_out, int out_size, void* d_ws, size_t ws_size,
                              hipStream_t stream) {
    (void)in_sizes; (void)n_in; (void)out_size; (void)ws_size;
    const float* x     = (const float*)d_in[0];
    const float* h0    = (const float*)d_in[1];
    const float* c0    = (const float*)d_in[2];
    const float* W_in  = (const float*)d_in[3];
    const float* b_in  = (const float*)d_in[4];
    const float* W_ih  = (const float*)d_in[5];
    const float* W_hh  = (const float*)d_in[6];
    const float* b_ih  = (const float*)d_in[7];
    const float* b_hh  = (const float*)d_in[8];
    const float* W_out = (const float*)d_in[9];
    const float* b_out = (const float*)d_in[10];
    const float* ln_g  = (const float*)d_in[11];
    const float* ln_b  = (const float*)d_in[12];

    float* out   = (float*)d_out;
    short* h_all = (short*)d_ws;
    short* xp    = h_all + HALL_ELEMS;
    unsigned* cnt = (unsigned*)(xp + XP_ELEMS);
    const short* h3 = h_all + ((size_t)(3 * 257 + 1) << 16);

    (void)hipFuncSetAttribute(reinterpret_cast<const void*>(lstm_pipeline),
                              hipFuncAttributeMaxDynamicSharedMemorySize, PIPE_LDS);

    init_kernel<<<1024, 256, 0, stream>>>(h_all, cnt, h0);
    gemm_xp<<<dim3(256, 4), 256, 0, stream>>>(x, W_in, b_in, xp);
    lstm_pipeline<<<256, 512, PIPE_LDS, stream>>>(xp, h_all, cnt, W_ih, W_hh,
                                                  b_ih, b_hh, c0, out);
    gemm_out<<<dim3(256, 6), 256, 0, stream>>>(h3, W_out, b_out, out);
    ln_kernel<<<32768, 256, 0, stream>>>(out, ln_g, ln_b);
}

// Round 4
// 5458.267 us; speedup vs baseline: 2.9386x; 1.7871x over previous
//
#include <hip/hip_runtime.h>
#include <math.h>

#define T_SEQ 256
#define BATCH 128
#define HID 512
#define NL 4
// d_out: out [128][256][768] fp32 | hT [4][128][512] | cT [4][128][512]
#define HT_OFF 25165824u
#define CT_OFF 25427968u
// ws: h_all bf16 [4][257][128][512] | xp bf16 [256][128][512] | flags [4][256][64]
#define HALL_ELEMS 67371008u
#define XP_ELEMS   16777216u
#define FLG_OFF(l,t) ((((l) << 8) + (t)) << 6)   // 64 dwords per (l,t)

typedef __attribute__((ext_vector_type(8))) short bf16x8;
typedef __attribute__((ext_vector_type(4))) float f32x4;

__device__ __forceinline__ short f2bf(float f) {
    unsigned u = __float_as_uint(f);
    u = (u + 0x7fffu + ((u >> 16) & 1u)) >> 16;
    return (short)u;
}
__device__ __forceinline__ unsigned pack2(float a, float b) {
    return ((unsigned)(unsigned short)f2bf(a)) |
           (((unsigned)(unsigned short)f2bf(b)) << 16);
}
// race-exposed load: 16B fragment via two 8B agent-scope (sc1) atomic loads,
// bypassing L1/L2 so we read the LLC coherence point the producers stored to.
__device__ __forceinline__ bf16x8 ld8_sc1(const short* p) {
    unsigned long long q0 = __hip_atomic_load((const unsigned long long*)p,
                                              __ATOMIC_RELAXED, __HIP_MEMORY_SCOPE_AGENT);
    unsigned long long q1 = __hip_atomic_load((const unsigned long long*)(p + 4),
                                              __ATOMIC_RELAXED, __HIP_MEMORY_SCOPE_AGENT);
    union { unsigned long long q[2]; bf16x8 v; } u;
    u.q[0] = q0; u.q[1] = q1;
    return u.v;
}

// ---------------------------------------------------------------------------
__global__ void init_kernel(short* __restrict__ h_all, unsigned* __restrict__ flg,
                            const float* __restrict__ h0) {
    int idx = blockIdx.x * 256 + threadIdx.x;       // grid 1024*256
    if (idx < NL * BATCH * HID) {
        int l = idx >> 16, rest = idx & 65535;
        h_all[((size_t)(l * 257) << 16) + rest] = f2bf(h0[idx]);
    }
    if (idx < NL * T_SEQ * 64) flg[idx] = 0u;
}

// ---------------------------------------------------------------------------
// xp-GEMM: xp[t][b][n] (bf16) = x[b][t][:768] @ W_in[n][:768] + b_in[n]
// ---------------------------------------------------------------------------
__global__ __launch_bounds__(256) void gemm_xp(const float* __restrict__ x,
                                               const float* __restrict__ W_in,
                                               const float* __restrict__ b_in,
                                               short* __restrict__ xp) {
    __shared__ short As[128 * 72];
    __shared__ short Bs[128 * 72];
    const int tid = threadIdx.x;
    const int w = tid >> 6, lane = tid & 63;
    const int m = lane & 15, quad = lane >> 4;
    const int rowbase = blockIdx.x * 128;           // M = 32768 (b*256+t)
    const int colbase = blockIdx.y * 128;           // N = 512
    f32x4 acc[2][8];
#pragma unroll
    for (int rt = 0; rt < 2; ++rt)
#pragma unroll
        for (int ct = 0; ct < 8; ++ct) { f32x4 z = {0.f,0.f,0.f,0.f}; acc[rt][ct] = z; }

    for (int k0 = 0; k0 < 768; k0 += 64) {
        __syncthreads();
#pragma unroll
        for (int i = 0; i < 8; ++i) {
            int q = tid + (i << 8);
            int r = q >> 4, f4 = (q & 15) << 2;
            float4 v = *(const float4*)(x + (size_t)(rowbase + r) * 768 + k0 + f4);
            uint2 p; p.x = pack2(v.x, v.y); p.y = pack2(v.z, v.w);
            *(uint2*)&As[r * 72 + f4] = p;
        }
#pragma unroll
        for (int i = 0; i < 8; ++i) {
            int q = tid + (i << 8);
            int r = q >> 4, f4 = (q & 15) << 2;
            float4 v = *(const float4*)(W_in + (size_t)(colbase + r) * 768 + k0 + f4);
            uint2 p; p.x = pack2(v.x, v.y); p.y = pack2(v.z, v.w);
            *(uint2*)&Bs[r * 72 + f4] = p;
        }
        __syncthreads();
#pragma unroll
        for (int ks = 0; ks < 2; ++ks) {
            int kof = (ks << 5) + (quad << 3);
            bf16x8 a0 = *(const bf16x8*)&As[((w * 2 + 0) * 16 + m) * 72 + kof];
            bf16x8 a1 = *(const bf16x8*)&As[((w * 2 + 1) * 16 + m) * 72 + kof];
#pragma unroll
            for (int ct = 0; ct < 8; ++ct) {
                bf16x8 b = *(const bf16x8*)&Bs[(ct * 16 + m) * 72 + kof];
                acc[0][ct] = __builtin_amdgcn_mfma_f32_16x16x32_bf16(a0, b, acc[0][ct], 0, 0, 0);
                acc[1][ct] = __builtin_amdgcn_mfma_f32_16x16x32_bf16(a1, b, acc[1][ct], 0, 0, 0);
            }
        }
    }
    float bias_r[8];
#pragma unroll
    for (int ct = 0; ct < 8; ++ct) bias_r[ct] = b_in[colbase + ct * 16 + m];
#pragma unroll
    for (int rt = 0; rt < 2; ++rt)
#pragma unroll
        for (int reg = 0; reg < 4; ++reg) {
            int m_glob = rowbase + (w * 2 + rt) * 16 + quad * 4 + reg;
            int t = m_glob & 255, b = m_glob >> 8;
            short* dst = xp + (((size_t)(t << 7) + b) << 9);
#pragma unroll
            for (int ct = 0; ct < 8; ++ct)
                dst[colbase + ct * 16 + m] = f2bf(acc[rt][ct][reg] + bias_r[ct]);
        }
}

// ---------------------------------------------------------------------------
// out-GEMM: out[b][t][n] (fp32) = h3[t][b][:512] @ W_out[n][:512] + b_out[n]
// ---------------------------------------------------------------------------
__global__ __launch_bounds__(256) void gemm_out(const short* __restrict__ h3,
                                                const float* __restrict__ W_out,
                                                const float* __restrict__ b_out,
                                                float* __restrict__ out) {
    __shared__ short As[128 * 72];
    __shared__ short Bs[128 * 72];
    const int tid = threadIdx.x;
    const int w = tid >> 6, lane = tid & 63;
    const int m = lane & 15, quad = lane >> 4;
    const int rowbase = blockIdx.x * 128;           // M = 32768 (t*128+b)
    const int colbase = blockIdx.y * 128;           // N = 768
    f32x4 acc[2][8];
#pragma unroll
    for (int rt = 0; rt < 2; ++rt)
#pragma unroll
        for (int ct = 0; ct < 8; ++ct) { f32x4 z = {0.f,0.f,0.f,0.f}; acc[rt][ct] = z; }

    for (int k0 = 0; k0 < 512; k0 += 64) {
        __syncthreads();
#pragma unroll
        for (int i = 0; i < 4; ++i) {
            int q = tid + (i << 8);
            int r = q >> 3, seg = (q & 7) << 3;
            *(bf16x8*)&As[r * 72 + seg] =
                *(const bf16x8*)(h3 + (size_t)(rowbase + r) * 512 + k0 + seg);
        }
#pragma unroll
        for (int i = 0; i < 8; ++i) {
            int q = tid + (i << 8);
            int r = q >> 4, f4 = (q & 15) << 2;
            float4 v = *(const float4*)(W_out + (size_t)(colbase + r) * 512 + k0 + f4);
            uint2 p; p.x = pack2(v.x, v.y); p.y = pack2(v.z, v.w);
            *(uint2*)&Bs[r * 72 + f4] = p;
        }
        __syncthreads();
#pragma unroll
        for (int ks = 0; ks < 2; ++ks) {
            int kof = (ks << 5) + (quad << 3);
            bf16x8 a0 = *(const bf16x8*)&As[((w * 2 + 0) * 16 + m) * 72 + kof];
            bf16x8 a1 = *(const bf16x8*)&As[((w * 2 + 1) * 16 + m) * 72 + kof];
#pragma unroll
            for (int ct = 0; ct < 8; ++ct) {
                bf16x8 b = *(const bf16x8*)&Bs[(ct * 16 + m) * 72 + kof];
                acc[0][ct] = __builtin_amdgcn_mfma_f32_16x16x32_bf16(a0, b, acc[0][ct], 0, 0, 0);
                acc[1][ct] = __builtin_amdgcn_mfma_f32_16x16x32_bf16(a1, b, acc[1][ct], 0, 0, 0);
            }
        }
    }
    float bias_r[8];
#pragma unroll
    for (int ct = 0; ct < 8; ++ct) bias_r[ct] = b_out[colbase + ct * 16 + m];
#pragma unroll
    for (int rt = 0; rt < 2; ++rt)
#pragma unroll
        for (int reg = 0; reg < 4; ++reg) {
            int m_glob = rowbase + (w * 2 + rt) * 16 + quad * 4 + reg;
            int t = m_glob >> 7, b = m_glob & 127;
            float* dst = out + (size_t)b * 196608 + (size_t)t * 768;
#pragma unroll
            for (int ct = 0; ct < 8; ++ct)
                dst[colbase + ct * 16 + m] = acc[rt][ct][reg] + bias_r[ct];
        }
}

// ---------------------------------------------------------------------------
// Persistent MFMA LSTM pipeline. 256 blocks = 4 layers x 64 col-chunks,
// 512 thr = 8 waves. Waves 0-3: x-part (W_ih), waves 4-7: h-part (W_hh).
// Weights in 128 VGPRs/lane. h written via relaxed agent (sc1) stores -> LLC;
// per-block flag dword; consumers poll 64 flags wave-wide (relaxed) and read
// race-exposed h via sc1 atomic loads (bypass stale L1/L2 copies).
// ---------------------------------------------------------------------------
__global__ __launch_bounds__(512, 2) void lstm_pipeline(
    const short* __restrict__ xp, short* __restrict__ h_all,
    unsigned* __restrict__ flg,
    const float* __restrict__ W_ih, const float* __restrict__ W_hh,
    const float* __restrict__ b_ih, const float* __restrict__ b_hh,
    const float* __restrict__ c0, float* __restrict__ d_out) {
    __shared__ float gates[128 * 33];
    __shared__ float cL[128 * 8];
    __shared__ float biasL[32];

    const int tid = threadIdx.x;
    const int l = blockIdx.x >> 6, c = blockIdx.x & 63;
    const int w = tid >> 6, lane = tid & 63;
    const int m = lane & 15, quad = lane >> 4;
    const bool hw = (w >= 4);
    const int w2 = w & 3;

    // --- load weight fragments into registers (once) ---
    const float* Wsrc = hw ? W_hh : W_ih;
    bf16x8 wf[32];
#pragma unroll
    for (int ks = 0; ks < 16; ++ks) {
#pragma unroll
        for (int ct = 0; ct < 2; ++ct) {
            int u = ct * 16 + m;
            int gr = ((u >> 3) << 9) + (c << 3) + (u & 7);
            const float* s = Wsrc + ((size_t)(l * 2048 + gr) << 9) + ks * 32 + quad * 8;
            float4 v0 = *(const float4*)s;
            float4 v1 = *(const float4*)(s + 4);
            uint4 p;
            p.x = pack2(v0.x, v0.y); p.y = pack2(v0.z, v0.w);
            p.z = pack2(v1.x, v1.y); p.w = pack2(v1.z, v1.w);
            wf[ks * 2 + ct] = *(bf16x8*)&p;
        }
    }
    if (tid < 32) {
        int gr = ((tid >> 3) << 9) + (c << 3) + (tid & 7);
        biasL[tid] = b_ih[l * 2048 + gr] + b_hh[l * 2048 + gr];
    }
    for (int p = tid; p < 1024; p += 512) {
        int r = p >> 3, hc = p & 7;
        cL[p] = c0[((size_t)l << 16) + (r << 9) + (c << 3) + hc];
    }
    __syncthreads();

    const int er = tid >> 2, eq = (tid & 3) << 1;    // elementwise: row, col-pair

    for (int t = 0; t < T_SEQ; ++t) {
        // --- per-wave dependency poll (relaxed agent loads, lane i = flag i) ---
        if (hw) {
            if (t > 0) {
                const unsigned* f = flg + FLG_OFF(l, t - 1) + lane;
                unsigned v = __hip_atomic_load(f, __ATOMIC_RELAXED, __HIP_MEMORY_SCOPE_AGENT);
                while (__any(v == 0u)) {
                    __builtin_amdgcn_s_sleep(1);
                    v = __hip_atomic_load(f, __ATOMIC_RELAXED, __HIP_MEMORY_SCOPE_AGENT);
                }
            }
        } else if (l > 0) {
            const unsigned* f = flg + FLG_OFF(l - 1, t) + lane;
            unsigned v = __hip_atomic_load(f, __ATOMIC_RELAXED, __HIP_MEMORY_SCOPE_AGENT);
            while (__any(v == 0u)) {
                __builtin_amdgcn_s_sleep(1);
                v = __hip_atomic_load(f, __ATOMIC_RELAXED, __HIP_MEMORY_SCOPE_AGENT);
            }
        }
        asm volatile("" ::: "memory");               // keep A-loads below the poll

        f32x4 z = {0.f, 0.f, 0.f, 0.f};
        f32x4 acc00 = z, acc01 = z, acc10 = z, acc11 = z;

        if (!hw && l == 0) {
            // race-free path: xp written by a prior dispatch -> plain cached loads
            const short* src = xp + ((size_t)t << 16);
#pragma unroll
            for (int ks = 0; ks < 16; ++ks) {
                int ka = ks * 32 + quad * 8;
                bf16x8 a0 = *(const bf16x8*)(src + ((size_t)(w2 * 32 + m) << 9) + ka);
                bf16x8 a1 = *(const bf16x8*)(src + ((size_t)(w2 * 32 + 16 + m) << 9) + ka);
                acc00 = __builtin_amdgcn_mfma_f32_16x16x32_bf16(a0, wf[ks * 2 + 0], acc00, 0, 0, 0);
                acc01 = __builtin_amdgcn_mfma_f32_16x16x32_bf16(a0, wf[ks * 2 + 1], acc01, 0, 0, 0);
                acc10 = __builtin_amdgcn_mfma_f32_16x16x32_bf16(a1, wf[ks * 2 + 0], acc10, 0, 0, 0);
                acc11 = __builtin_amdgcn_mfma_f32_16x16x32_bf16(a1, wf[ks * 2 + 1], acc11, 0, 0, 0);
            }
        } else {
            // race-exposed path: h written by other blocks this dispatch -> sc1 loads
            const short* src = hw
                ? (h_all + ((size_t)(l * 257 + t) << 16))
                : (h_all + ((size_t)((l - 1) * 257 + t + 1) << 16));
#pragma unroll
            for (int ks = 0; ks < 16; ++ks) {
                int ka = ks * 32 + quad * 8;
                bf16x8 a0 = ld8_sc1(src + ((size_t)(w2 * 32 + m) << 9) + ka);
                bf16x8 a1 = ld8_sc1(src + ((size_t)(w2 * 32 + 16 + m) << 9) + ka);
                acc00 = __builtin_amdgcn_mfma_f32_16x16x32_bf16(a0, wf[ks * 2 + 0], acc00, 0, 0, 0);
                acc01 = __builtin_amdgcn_mfma_f32_16x16x32_bf16(a0, wf[ks * 2 + 1], acc01, 0, 0, 0);
                acc10 = __builtin_amdgcn_mfma_f32_16x16x32_bf16(a1, wf[ks * 2 + 0], acc10, 0, 0, 0);
                acc11 = __builtin_amdgcn_mfma_f32_16x16x32_bf16(a1, wf[ks * 2 + 1], acc11, 0, 0, 0);
            }
        }
        const int gb0 = w2 * 32 + quad * 4;
        if (!hw) {
#pragma unroll
            for (int reg = 0; reg < 4; ++reg) {
                gates[(gb0 + reg) * 33 + m]           = acc00[reg];
                gates[(gb0 + reg) * 33 + 16 + m]      = acc01[reg];
                gates[(gb0 + 16 + reg) * 33 + m]      = acc10[reg];
                gates[(gb0 + 16 + reg) * 33 + 16 + m] = acc11[reg];
            }
        }
        __syncthreads();                             // B1: x-part visible
        if (hw) {
#pragma unroll
            for (int reg = 0; reg < 4; ++reg) {
                gates[(gb0 + reg) * 33 + m]           += acc00[reg];
                gates[(gb0 + reg) * 33 + 16 + m]      += acc01[reg];
                gates[(gb0 + 16 + reg) * 33 + m]      += acc10[reg];
                gates[(gb0 + 16 + reg) * 33 + 16 + m] += acc11[reg];
            }
        }
        __syncthreads();                             // B2: gates complete

        // --- elementwise: 2 adjacent cells per thread, packed dword sc1 store ---
        float hv[2], cv[2];
#pragma unroll
        for (int e = 0; e < 2; ++e) {
            int hc = eq + e;
            float iv = gates[er * 33 + hc]      + biasL[hc];
            float fv = gates[er * 33 + 8 + hc]  + biasL[8 + hc];
            float gv = gates[er * 33 + 16 + hc] + biasL[16 + hc];
            float ov = gates[er * 33 + 24 + hc] + biasL[24 + hc];
            float ig = 1.f / (1.f + __expf(-iv));
            float fg = 1.f / (1.f + __expf(-fv));
            float gg = tanhf(gv);
            float og = 1.f / (1.f + __expf(-ov));
            float cn = fg * cL[er * 8 + hc] + ig * gg;
            float hn = og * tanhf(cn);
            cL[er * 8 + hc] = cn;
            hv[e] = hn; cv[e] = cn;
        }
        unsigned pk = pack2(hv[0], hv[1]);
        unsigned* hdst = (unsigned*)(h_all + ((size_t)(l * 257 + t + 1) << 16)
                                     + (er << 9) + (c << 3) + eq);
        __hip_atomic_store(hdst, pk, __ATOMIC_RELAXED, __HIP_MEMORY_SCOPE_AGENT);
        if (t == T_SEQ - 1) {
            size_t fo = ((size_t)l << 16) + (size_t)(er << 9) + (c << 3) + eq;
            d_out[HT_OFF + fo]     = hv[0];
            d_out[HT_OFF + fo + 1] = hv[1];
            d_out[CT_OFF + fo]     = cv[0];
            d_out[CT_OFF + fo + 1] = cv[1];
        }
        __syncthreads();                             // B3: drains all sc1 stores
        if (tid == 0)
            __hip_atomic_store(flg + FLG_OFF(l, t) + c, 1u,
                               __ATOMIC_RELAXED, __HIP_MEMORY_SCOPE_AGENT);
    }
}

// ---------------------------------------------------------------------------
__global__ __launch_bounds__(256) void ln_kernel(float* __restrict__ out,
                                                 const float* __restrict__ g,
                                                 const float* __restrict__ bvec) {
    float* p = out + (size_t)blockIdx.x * 768;
    int tid = threadIdx.x;
    float v0 = p[tid], v1 = p[tid + 256], v2 = p[tid + 512];
    float s = v0 + v1 + v2;
    float q = v0 * v0 + v1 * v1 + v2 * v2;
    for (int off = 32; off > 0; off >>= 1) {
        s += __shfl_down(s, off);
        q += __shfl_down(q, off);
    }
    __shared__ float ss[4], qq[4];
    __shared__ float mu_s, rs_s;
    int w = tid >> 6;
    if ((tid & 63) == 0) { ss[w] = s; qq[w] = q; }
    __syncthreads();
    if (tid == 0) {
        float S = ss[0] + ss[1] + ss[2] + ss[3];
        float Q = qq[0] + qq[1] + qq[2] + qq[3];
        float mu = S * (1.f / 768.f);
        float var = Q * (1.f / 768.f) - mu * mu;
        mu_s = mu;
        rs_s = rsqrtf(var + 1e-5f);
    }
    __syncthreads();
    float mu = mu_s, rs = rs_s;
    p[tid]       = (v0 - mu) * rs * g[tid]       + bvec[tid];
    p[tid + 256] = (v1 - mu) * rs * g[tid + 256] + bvec[tid + 256];
    p[tid + 512] = (v2 - mu) * rs * g[tid + 512] + bvec[tid + 512];
}

// ---------------------------------------------------------------------------
extern "C" void kernel_launch(void* const* d_in, const int* in_sizes, int n_in,
                              void* d_out, int out_size, void* d_ws, size_t ws_size,
                              hipStream_t stream) {
    (void)in_sizes; (void)n_in; (void)out_size; (void)ws_size;
    const float* x     = (const float*)d_in[0];
    const float* h0    = (const float*)d_in[1];
    const float* c0    = (const float*)d_in[2];
    const float* W_in  = (const float*)d_in[3];
    const float* b_in  = (const float*)d_in[4];
    const float* W_ih  = (const float*)d_in[5];
    const float* W_hh  = (const float*)d_in[6];
    const float* b_ih  = (const float*)d_in[7];
    const float* b_hh  = (const float*)d_in[8];
    const float* W_out = (const float*)d_in[9];
    const float* b_out = (const float*)d_in[10];
    const float* ln_g  = (const float*)d_in[11];
    const float* ln_b  = (const float*)d_in[12];

    float* out   = (float*)d_out;
    short* h_all = (short*)d_ws;
    short* xp    = h_all + HALL_ELEMS;
    unsigned* flg = (unsigned*)(xp + XP_ELEMS);
    const short* h3 = h_all + ((size_t)(3 * 257 + 1) << 16);

    init_kernel<<<1024, 256, 0, stream>>>(h_all, flg, h0);
    gemm_xp<<<dim3(256, 4), 256, 0, stream>>>(x, W_in, b_in, xp);
    lstm_pipeline<<<256, 512, 0, stream>>>(xp, h_all, flg, W_ih, W_hh,
                                           b_ih, b_hh, c0, out);
    gemm_out<<<dim3(256, 6), 256, 0, stream>>>(h3, W_out, b_out, out);
    ln_kernel<<<32768, 256, 0, stream>>>(out, ln_g, ln_b);
}